// Round 5
// baseline (282.542 us; speedup 1.0000x reference)
//
#include <hip/hip_runtime.h>
#include <hip/hip_bf16.h>

// Problem constants
#define B_ROWS 32768
#define LN_EPS 1e-5f
// GEMM2 N used = 288 (18 groups of 16): 256 (Z) + 25 (yt via folded C) + pad
// GEMM2 K = 544: 512 (H') + 16 (ut*dt) + 1 (const) + 15 pad; kk2 in [0,17)

typedef __bf16 bf16;
using bf16x4 = __attribute__((ext_vector_type(4))) __bf16;
using bf16x8 = __attribute__((ext_vector_type(8))) __bf16;
using f32x4  = __attribute__((ext_vector_type(4))) float;

// ---------------- workspace layout (bytes) ----------------
// W1sw [32G][10kk][4q][16m][8e] bf16 : 327,680 @ 0
// Psw  [20G][17kk][4q][16m][8e] bf16 : 348,160 @ 327,680
// Mtmp [4,64,128] f32               : 131,072 @ 675,840
// cvec [256] f32                    :   1,024 @ 806,912
// CW   [25,4,64] f32                :  25,600 @ 807,936
// total ~0.8 MB (keep ws small: harness re-poison of d_ws is timed)

// exact-GELU via A&S 7.1.26 rational erf (|eps| <= 1.5e-7), branch-free
__device__ __forceinline__ float gelu_exact(float x) {
  float s = x * 0.70710678118f;
  float a = fabsf(s);
  float t = __builtin_amdgcn_rcpf(fmaf(0.3275911f, a, 1.0f));
  float p = fmaf(fmaf(fmaf(fmaf(1.061405429f, t, -1.453152027f),
                           t, 1.421413741f), t, -0.284496736f), t, 0.254829592f) * t;
  float e = __expf(-s * s);
  float er = fmaf(-p, e, 1.0f);
  er = copysignf(er, s);
  return 0.5f * x * (1.0f + er);
}

// ---------------- prep 1: W1sw (gate-folded, fragment-swizzled layout),
// Mtmp = BmatG*W2, cvec = BmatG*b2, CW[o,n,r] = sum_d C[o,d]*Wout[n,d,r]
__global__ __launch_bounds__(256) void prep_weights1(
    const float* __restrict__ gates, const float* __restrict__ W1,
    const float* __restrict__ Bmat,  const float* __restrict__ W2,
    const float* __restrict__ b2,    const float* __restrict__ Wout,
    const float* __restrict__ Cm,
    bf16* __restrict__ W1sw, float* __restrict__ Mtmp, float* __restrict__ cvec,
    float* __restrict__ CW)
{
  const int stride = gridDim.x * blockDim.x;
  const int id = blockIdx.x * blockDim.x + threadIdx.x;
  // swizzled layout: o = ((G*10+kk)*4+q)*128 + m*8 + e ; n = G*16+m, k = kk*32+q*8+e
  for (int o = id; o < 512 * 320; o += stride) {
    int e = o & 7, m = (o >> 3) & 15, q2 = (o >> 7) & 3, rest = o >> 9;
    int kk = rest % 10, G = rest / 10;
    int n = G * 16 + m, k = kk * 32 + q2 * 8 + e;
    float wv = W1[n * 320 + k];
    if (k < 256) {
      float g = gates[(n >> 7) * 256 + k];
      wv *= 1.f / (1.f + __expf(-g));
    }
    W1sw[o] = (bf16)wv;
  }
  for (int i = id; i < 4 * 64 * 128; i += stride) {
    int n = i >> 13, r = (i >> 7) & 63, h = i & 127;
    float s = 0.f;
    for (int j = 0; j < 64; ++j)
      s += Bmat[(n * 64 + r) * 80 + j] * W2[(n * 64 + j) * 128 + h];
    Mtmp[i] = s;
  }
  for (int i = id; i < 256; i += stride) {
    int n = i >> 6, r = i & 63;
    float s = 0.f;
    for (int j = 0; j < 64; ++j)
      s += Bmat[(n * 64 + r) * 80 + j] * b2[n * 64 + j];
    cvec[i] = s;
  }
  for (int i = id; i < 25 * 256; i += stride) {
    int o = i >> 8, nr = i & 255;
    float s = 0.f;
    for (int d = 0; d < 256; ++d)
      s += Cm[o * 256 + d] * Wout[((nr >> 6) * 256 + d) * 64 + (nr & 63)];
    CW[i] = s;
  }
}

// ---------------- prep 2: Psw fragment-swizzled [320 rows][544 cols]
// rows 0..255 (d): [P | Q | czn | 0]; rows 256..280 (o): [C*P | C*Q + D | C*czn | 0];
// rows 281..319: 0
__global__ __launch_bounds__(256) void prep_weights2(
    const float* __restrict__ Wout, const float* __restrict__ Bmat,
    const float* __restrict__ Mtmp, const float* __restrict__ cvec,
    const float* __restrict__ CW,   const float* __restrict__ Dm,
    bf16* __restrict__ Psw)
{
  const int stride = gridDim.x * blockDim.x;
  const int id = blockIdx.x * blockDim.x + threadIdx.x;
  for (int o = id; o < 320 * 544; o += stride) {
    int e = o & 7, m = (o >> 3) & 15, q2 = (o >> 7) & 3, rest = o >> 9;
    int kk2 = rest % 17, G2 = rest / 17;
    int dd = G2 * 16 + m, cc = kk2 * 32 + q2 * 8 + e;
    float s = 0.f;
    if (dd < 281) {
      const bool isC = (dd >= 256);
      const int oo = dd - 256;
      if (cc < 512) {
        int n = cc >> 7, h = cc & 127;
        for (int r = 0; r < 64; ++r) {
          float wv = isC ? CW[(oo * 4 + n) * 64 + r] : Wout[(n * 256 + dd) * 64 + r];
          s += wv * Mtmp[(n * 64 + r) * 128 + h];
        }
      } else if (cc < 528) {
        int u = cc - 512;
        for (int n = 0; n < 4; ++n)
          for (int r = 0; r < 64; ++r) {
            float wv = isC ? CW[(oo * 4 + n) * 64 + r] : Wout[(n * 256 + dd) * 64 + r];
            s += wv * Bmat[(n * 64 + r) * 80 + 64 + u];
          }
        if (isC) s += Dm[oo * 16 + u];
      } else if (cc == 528) {
        for (int n = 0; n < 4; ++n)
          for (int r = 0; r < 64; ++r) {
            float wv = isC ? CW[(oo * 4 + n) * 64 + r] : Wout[(n * 256 + dd) * 64 + r];
            s += wv * cvec[n * 64 + r];
          }
      }
    }
    Psw[o] = (bf16)s;
  }
}

// ---------------- fused main v3: wave-private rows, single barrier.
// Wave w owns batch rows [blk*64 + w*16, +16). X in registers (bf16 frags).
// GEMM1 computed as H^T (A = W1 frags, B = X frags) -> LN stats intra-wave via
// shfl_xor -> GELU in-register -> per-wave LDS transpose (b64 writes, b128
// reads, double-buffered) -> GEMM2 (A = H, B = Psw frags) -> Z/yt.
__global__ __launch_bounds__(256, 2) void fused_main(
    const float* __restrict__ zdyn, const float* __restrict__ zst,
    const float* __restrict__ ut,   const float* __restrict__ dtp,
    const bf16* __restrict__ W1sw,  const bf16* __restrict__ Psw,
    const float* __restrict__ b1,   const float* __restrict__ gamma,
    const float* __restrict__ beta,
    float* __restrict__ Z, float* __restrict__ yt)
{
  __shared__ __align__(16) bf16 Hw[2][4][16 * 136];  // 34.8 KB: per-wave transpose tiles
  __shared__ float sb1[512], sgam[512], sbet[512];   // 6 KB

  const int t = threadIdx.x;
  const int lane = t & 63, m16 = lane & 15, q = lane >> 4;
  const int w = t >> 6;
  const int rowBase = blockIdx.x * 64 + w * 16;      // wave's 16 batch rows

  sb1[t] = b1[t];   sb1[t + 256] = b1[t + 256];
  sgam[t] = gamma[t]; sgam[t + 256] = gamma[t + 256];
  sbet[t] = beta[t];  sbet[t + 256] = beta[t + 256];
  __syncthreads();   // the only block-wide barrier

  // ---- X into registers: lane holds X[batch = rowBase+m16][k = kk*32+q*8+e]
  bf16x8 Xreg[10];
  {
    const float* zrow = zdyn + (size_t)(rowBase + m16) * 256 + q * 8;
    #pragma unroll
    for (int kk = 0; kk < 8; ++kk) {
      float4 v0 = *(const float4*)(zrow + kk * 32);
      float4 v1 = *(const float4*)(zrow + kk * 32 + 4);
      Xreg[kk][0]=(bf16)v0.x; Xreg[kk][1]=(bf16)v0.y; Xreg[kk][2]=(bf16)v0.z; Xreg[kk][3]=(bf16)v0.w;
      Xreg[kk][4]=(bf16)v1.x; Xreg[kk][5]=(bf16)v1.y; Xreg[kk][6]=(bf16)v1.z; Xreg[kk][7]=(bf16)v1.w;
    }
    const float* srow = zst + (size_t)(rowBase + m16) * 64 + q * 8;
    #pragma unroll
    for (int kk = 8; kk < 10; ++kk) {
      float4 v0 = *(const float4*)(srow + (kk - 8) * 32);
      float4 v1 = *(const float4*)(srow + (kk - 8) * 32 + 4);
      Xreg[kk][0]=(bf16)v0.x; Xreg[kk][1]=(bf16)v0.y; Xreg[kk][2]=(bf16)v0.z; Xreg[kk][3]=(bf16)v0.w;
      Xreg[kk][4]=(bf16)v1.x; Xreg[kk][5]=(bf16)v1.y; Xreg[kk][6]=(bf16)v1.z; Xreg[kk][7]=(bf16)v1.w;
    }
  }

  // ---- K-tail A-frag: [ut*dt | 1 | 0] for this lane's rows
  bf16x8 utreg;
  {
    const float dtv = dtp[0];
    if (q < 2) {
      const float* up = ut + (size_t)(rowBase + m16) * 16 + q * 8;
      float4 u0 = *(const float4*)up, u1 = *(const float4*)(up + 4);
      utreg[0]=(bf16)(u0.x*dtv); utreg[1]=(bf16)(u0.y*dtv); utreg[2]=(bf16)(u0.z*dtv); utreg[3]=(bf16)(u0.w*dtv);
      utreg[4]=(bf16)(u1.x*dtv); utreg[5]=(bf16)(u1.y*dtv); utreg[6]=(bf16)(u1.z*dtv); utreg[7]=(bf16)(u1.w*dtv);
    } else {
      #pragma unroll
      for (int e = 0; e < 8; ++e) utreg[e] = (bf16)0.f;
      if (q == 2) utreg[0] = (bf16)1.f;
    }
  }

  f32x4 accZ[18];
  #pragma unroll
  for (int j = 0; j < 18; ++j)
    #pragma unroll
    for (int r = 0; r < 4; ++r) accZ[j][r] = 0.f;

  #pragma unroll 1
  for (int c = 0; c < 4; ++c) {
    // ---- phase 1: acc1[j] = (W1_c * X^T) tile -> lane holds
    //      H[h-col = j*16 + q*4 + rr][batch = m16]
    f32x4 acc1[8];
    #pragma unroll
    for (int j = 0; j < 8; ++j)
      #pragma unroll
      for (int r = 0; r < 4; ++r) acc1[j][r] = 0.f;

    #pragma unroll
    for (int kk = 0; kk < 10; ++kk) {
      const bf16* bp = W1sw + (size_t)(c * 80 + kk) * 512 + q * 128 + m16 * 8;
      #pragma unroll
      for (int j = 0; j < 8; ++j) {
        bf16x8 afw = *(const bf16x8*)(bp + j * 5120);
        acc1[j] = __builtin_amdgcn_mfma_f32_16x16x32_bf16(afw, Xreg[kk], acc1[j], 0, 0, 0);
      }
    }

    // ---- +b1, intra-wave LN stats (per batch row = per m16 lane-column)
    float s = 0.f, s2 = 0.f;
    #pragma unroll
    for (int j = 0; j < 8; ++j) {
      float4 bv = *(const float4*)&sb1[c * 128 + j * 16 + q * 4];
      #pragma unroll
      for (int r = 0; r < 4; ++r) {
        float v = acc1[j][r] + (&bv.x)[r];
        acc1[j][r] = v;
        s += v; s2 = fmaf(v, v, s2);
      }
    }
    s  += __shfl_xor(s, 16);  s  += __shfl_xor(s, 32);
    s2 += __shfl_xor(s2, 16); s2 += __shfl_xor(s2, 32);
    float mu = s * 0.0078125f;
    float var = s2 * 0.0078125f - mu * mu;
    float rs = rsqrtf(fmaxf(var, 0.f) + LN_EPS);

    // ---- LN + GELU in-register, transpose via per-wave LDS (b64 writes)
    const int pg = c & 1;
    bf16* hw = &Hw[pg][w][0];
    #pragma unroll
    for (int j = 0; j < 8; ++j) {
      float4 gv = *(const float4*)&sgam[c * 128 + j * 16 + q * 4];
      float4 bv = *(const float4*)&sbet[c * 128 + j * 16 + q * 4];
      bf16x4 ov;
      #pragma unroll
      for (int r = 0; r < 4; ++r) {
        float v = (acc1[j][r] - mu) * rs;
        v = fmaf(v, (&gv.x)[r], (&bv.x)[r]);
        ov[r] = (bf16)gelu_exact(v);
      }
      *(bf16x4*)&hw[m16 * 136 + j * 16 + q * 4] = ov;
    }
    asm volatile("s_waitcnt lgkmcnt(0)" ::: "memory");

    // ---- phase 2: accZ += H_c * P_c^T (A-frags from Hw, barrier-free)
    #pragma unroll
    for (int t2 = 0; t2 < 4; ++t2) {
      bf16x8 af = *(const bf16x8*)&hw[m16 * 136 + t2 * 32 + q * 8];
      const bf16* pp = Psw + (size_t)(c * 4 + t2) * 512 + q * 128 + m16 * 8;
      #pragma unroll
      for (int j = 0; j < 18; ++j) {
        bf16x8 bfr = *(const bf16x8*)(pp + j * 8704);
        accZ[j] = __builtin_amdgcn_mfma_f32_16x16x32_bf16(af, bfr, accZ[j], 0, 0, 0);
      }
    }
    asm volatile("" ::: "memory");   // keep next branch's writes after these reads
  }

  // ---- K tail (kk2 = 16): A = [ut*dt | 1 | 0]
  {
    const bf16* pp = Psw + (size_t)16 * 512 + q * 128 + m16 * 8;
    #pragma unroll
    for (int j = 0; j < 18; ++j) {
      bf16x8 bfr = *(const bf16x8*)(pp + j * 8704);
      accZ[j] = __builtin_amdgcn_mfma_f32_16x16x32_bf16(utreg, bfr, accZ[j], 0, 0, 0);
    }
  }

  // ---- store Z / yt: lane (q,m16) reg (j,rr) -> row rowBase+q*4+rr, col j*16+m16
  #pragma unroll
  for (int j = 0; j < 18; ++j) {
    int col = j * 16 + m16;
    #pragma unroll
    for (int rr = 0; rr < 4; ++rr) {
      int row = rowBase + q * 4 + rr;
      if (col < 256)      Z[(size_t)row * 256 + col] = accZ[j][rr];
      else if (col < 281) yt[(size_t)row * 25 + (col - 256)] = accZ[j][rr];
    }
  }
}

extern "C" void kernel_launch(void* const* d_in, const int* in_sizes, int n_in,
                              void* d_out, int out_size, void* d_ws, size_t ws_size,
                              hipStream_t stream) {
  const float* zdyn  = (const float*)d_in[0];
  const float* zst   = (const float*)d_in[1];
  const float* dtp   = (const float*)d_in[2];
  const float* ut    = (const float*)d_in[3];
  const float* gates = (const float*)d_in[4];
  const float* W1    = (const float*)d_in[5];
  const float* b1    = (const float*)d_in[6];
  const float* gamma = (const float*)d_in[7];
  const float* beta  = (const float*)d_in[8];
  const float* W2    = (const float*)d_in[9];
  const float* b2    = (const float*)d_in[10];
  // d_in[11], d_in[12] (lam_real/lam_imag) dead: h0 = 0
  const float* Bmat  = (const float*)d_in[13];
  const float* Wout  = (const float*)d_in[14];
  const float* Cm    = (const float*)d_in[15];
  const float* Dm    = (const float*)d_in[16];

  char* ws = (char*)d_ws;
  bf16*  W1sw = (bf16*)(ws);
  bf16*  Psw  = (bf16*)(ws + 327680);
  float* Mtmp = (float*)(ws + 675840);
  float* cvec = (float*)(ws + 806912);
  float* CW   = (float*)(ws + 807936);

  float* Z  = (float*)d_out;
  float* yt = Z + (size_t)B_ROWS * 256;

  hipLaunchKernelGGL(prep_weights1, dim3(128), dim3(256), 0, stream,
                     gates, W1, Bmat, W2, b2, Wout, Cm, W1sw, Mtmp, cvec, CW);
  hipLaunchKernelGGL(prep_weights2, dim3(256), dim3(256), 0, stream,
                     Wout, Bmat, Mtmp, cvec, CW, Dm, Psw);
  hipLaunchKernelGGL(fused_main, dim3(512), dim3(256), 0, stream,
                     zdyn, zst, ut, dtp, W1sw, Psw, b1, gamma, beta, Z, yt);
}

// Round 7
// 190.780 us; speedup vs baseline: 1.4810x; 1.4810x over previous
//
#include <hip/hip_runtime.h>
#include <hip/hip_bf16.h>

// Problem constants
#define B_ROWS 32768
#define LN_EPS 1e-5f
// GEMM2 N used = 320 (20 groups of 16): 256 (Z) + 25 (yt via folded C) + pad
// GEMM2 K = 544: 512 (H') + 16 (ut*dt) + 1 (const) + 15 pad; kk2 in [0,17)

typedef __bf16 bf16;
using bf16x8 = __attribute__((ext_vector_type(8))) __bf16;
using f32x4  = __attribute__((ext_vector_type(4))) float;

// ---------------- workspace layout (bytes) ----------------
// W1sw [32G][10kk][4q][16m][8e] bf16 : 327,680 @ 0
// Psw  [20G][17kk][4q][16m][8e] bf16 : 348,160 @ 327,680
// Mtmp [4,64,128] f32               : 131,072 @ 675,840
// cvec [256] f32                    :   1,024 @ 806,912
// CW   [25,4,64] f32                :  25,600 @ 807,936
// total ~0.8 MB (keep ws small: harness re-poison of d_ws is timed)

// LDS-only barrier: orders DS ops across the block WITHOUT draining vmcnt,
// so global weight-fragment loads stay in flight across it.
__device__ __forceinline__ void lds_barrier() {
  asm volatile("s_waitcnt lgkmcnt(0)\n\ts_barrier" ::: "memory");
}

// exact-GELU via A&S 7.1.26 rational erf (|eps| <= 1.5e-7), branch-free
__device__ __forceinline__ float gelu_exact(float x) {
  float s = x * 0.70710678118f;
  float a = fabsf(s);
  float t = __builtin_amdgcn_rcpf(fmaf(0.3275911f, a, 1.0f));
  float p = fmaf(fmaf(fmaf(fmaf(1.061405429f, t, -1.453152027f),
                           t, 1.421413741f), t, -0.284496736f), t, 0.254829592f) * t;
  float e = __expf(-s * s);
  float er = fmaf(-p, e, 1.0f);
  er = copysignf(er, s);
  return 0.5f * x * (1.0f + er);
}

// ---------------- prep 1: W1sw (gate-folded, fragment-swizzled layout),
// Mtmp = BmatG*W2, cvec = BmatG*b2, CW[o,n,r] = sum_d C[o,d]*Wout[n,d,r]
__global__ __launch_bounds__(256) void prep_weights1(
    const float* __restrict__ gates, const float* __restrict__ W1,
    const float* __restrict__ Bmat,  const float* __restrict__ W2,
    const float* __restrict__ b2,    const float* __restrict__ Wout,
    const float* __restrict__ Cm,
    bf16* __restrict__ W1sw, float* __restrict__ Mtmp, float* __restrict__ cvec,
    float* __restrict__ CW)
{
  const int stride = gridDim.x * blockDim.x;
  const int id = blockIdx.x * blockDim.x + threadIdx.x;
  // swizzled layout: o = ((G*10+kk)*4+q)*128 + m*8 + e ; n = G*16+m, k = kk*32+q*8+e
  for (int o = id; o < 512 * 320; o += stride) {
    int e = o & 7, m = (o >> 3) & 15, q2 = (o >> 7) & 3, rest = o >> 9;
    int kk = rest % 10, G = rest / 10;
    int n = G * 16 + m, k = kk * 32 + q2 * 8 + e;
    float wv = W1[n * 320 + k];
    if (k < 256) {
      float g = gates[(n >> 7) * 256 + k];
      wv *= 1.f / (1.f + __expf(-g));
    }
    W1sw[o] = (bf16)wv;
  }
  for (int i = id; i < 4 * 64 * 128; i += stride) {
    int n = i >> 13, r = (i >> 7) & 63, h = i & 127;
    float s = 0.f;
    for (int j = 0; j < 64; ++j)
      s += Bmat[(n * 64 + r) * 80 + j] * W2[(n * 64 + j) * 128 + h];
    Mtmp[i] = s;
  }
  for (int i = id; i < 256; i += stride) {
    int n = i >> 6, r = i & 63;
    float s = 0.f;
    for (int j = 0; j < 64; ++j)
      s += Bmat[(n * 64 + r) * 80 + j] * b2[n * 64 + j];
    cvec[i] = s;
  }
  for (int i = id; i < 25 * 256; i += stride) {
    int o = i >> 8, nr = i & 255;
    float s = 0.f;
    for (int d = 0; d < 256; ++d)
      s += Cm[o * 256 + d] * Wout[((nr >> 6) * 256 + d) * 64 + (nr & 63)];
    CW[i] = s;
  }
}

// ---------------- prep 2: Psw fragment-swizzled [320 rows][544 cols]
// rows 0..255 (d): [P | Q | czn | 0]; rows 256..280 (o): [C*P | C*Q + D | C*czn | 0];
// rows 281..319: 0
__global__ __launch_bounds__(256) void prep_weights2(
    const float* __restrict__ Wout, const float* __restrict__ Bmat,
    const float* __restrict__ Mtmp, const float* __restrict__ cvec,
    const float* __restrict__ CW,   const float* __restrict__ Dm,
    bf16* __restrict__ Psw)
{
  const int stride = gridDim.x * blockDim.x;
  const int id = blockIdx.x * blockDim.x + threadIdx.x;
  for (int o = id; o < 320 * 544; o += stride) {
    int e = o & 7, m = (o >> 3) & 15, q2 = (o >> 7) & 3, rest = o >> 9;
    int kk2 = rest % 17, G2 = rest / 17;
    int dd = G2 * 16 + m, cc = kk2 * 32 + q2 * 8 + e;
    float s = 0.f;
    if (dd < 281) {
      const bool isC = (dd >= 256);
      const int oo = dd - 256;
      if (cc < 512) {
        int n = cc >> 7, h = cc & 127;
        for (int r = 0; r < 64; ++r) {
          float wv = isC ? CW[(oo * 4 + n) * 64 + r] : Wout[(n * 256 + dd) * 64 + r];
          s += wv * Mtmp[(n * 64 + r) * 128 + h];
        }
      } else if (cc < 528) {
        int u = cc - 512;
        for (int n = 0; n < 4; ++n)
          for (int r = 0; r < 64; ++r) {
            float wv = isC ? CW[(oo * 4 + n) * 64 + r] : Wout[(n * 256 + dd) * 64 + r];
            s += wv * Bmat[(n * 64 + r) * 80 + 64 + u];
          }
        if (isC) s += Dm[oo * 16 + u];
      } else if (cc == 528) {
        for (int n = 0; n < 4; ++n)
          for (int r = 0; r < 64; ++r) {
            float wv = isC ? CW[(oo * 4 + n) * 64 + r] : Wout[(n * 256 + dd) * 64 + r];
            s += wv * cvec[n * 64 + r];
          }
      }
    }
    Psw[o] = (bf16)s;
  }
}

// ---------------- fused main v5: R4 load-reuse structure + register LN (fixed).
// Block = 64 rows, 4 waves. A (X, then H) from LDS; B (W1sw/Psw frags) from
// L2, each load reused 4x. LN partials: per-lane over the wave's 2 cols,
// shfl_xor(1,2) across m16 -> spart[row][w*4+g] (w-indexed: no cross-wave
// race) -> t<64 final reduce. GELU in-register; H written to LDS once.
// All barriers are LDS-only (no vmcnt drain).
__global__ __launch_bounds__(256, 2) void fused_main(
    const float* __restrict__ zdyn, const float* __restrict__ zst,
    const float* __restrict__ ut,   const float* __restrict__ dtp,
    const bf16* __restrict__ W1sw,  const bf16* __restrict__ Psw,
    const float* __restrict__ b1,   const float* __restrict__ gamma,
    const float* __restrict__ beta,
    float* __restrict__ Z, float* __restrict__ yt)
{
  __shared__ __align__(16) bf16 Xs[64 * 320];       // 40 KB: X tile, swizzled
  __shared__ __align__(16) bf16 Hc[64 * 128];       // 16 KB: branch H tile, swizzled
  __shared__ __align__(16) bf16 Ht[64 * 32];        //  4 KB: [ut*dt | 1 | 0] K-tail
  __shared__ float sb1[512], sgam[512], sbet[512];  //  6 KB
  __shared__ float2 spart[64 * 17];                 // 8.5 KB: LN partials (pad 17)
  __shared__ __align__(16) float smu[64], srs[64];  //  0.5 KB
  // total ~75 KB -> 2 blocks/CU

  const int t = threadIdx.x;
  const int lane = t & 63, m16 = lane & 15, q = lane >> 4;
  const int w = t >> 6;
  const int rowBase = blockIdx.x * 64;

  sb1[t] = b1[t];   sb1[t + 256] = b1[t + 256];
  sgam[t] = gamma[t]; sgam[t + 256] = gamma[t + 256];
  sbet[t] = beta[t];  sbet[t + 256] = beta[t + 256];

  // ---- stage X: 64 rows x 320 cols f32 -> bf16 swizzled (2560 chunks of 8)
  #pragma unroll
  for (int a = 0; a < 10; ++a) {
    int g = a * 256 + t;
    int row = g / 40, pos = g - row * 40;
    int kk = pos >> 2, pq = pos & 3;
    int lq = pq ^ ((row >> 1) & 3);
    int col = kk * 32 + lq * 8;
    const float* src = (col < 256) ? &zdyn[(size_t)(rowBase + row) * 256 + col]
                                   : &zst[(size_t)(rowBase + row) * 64 + (col - 256)];
    float4 v0 = *(const float4*)src;
    float4 v1 = *(const float4*)(src + 4);
    bf16x8 o;
    o[0]=(bf16)v0.x; o[1]=(bf16)v0.y; o[2]=(bf16)v0.z; o[3]=(bf16)v0.w;
    o[4]=(bf16)v1.x; o[5]=(bf16)v1.y; o[6]=(bf16)v1.z; o[7]=(bf16)v1.w;
    *(bf16x8*)&Xs[(size_t)((kk * 64 + row) * 4 + pq) * 8] = o;
  }
  // ---- stage Ht: [ut*dt | 1 | 0]
  {
    const float dtv = dtp[0];
    int r = t >> 2, pq = t & 3;
    int lq = pq ^ ((r >> 1) & 3);
    bf16x8 o;
    #pragma unroll
    for (int e = 0; e < 8; ++e) {
      int ci = lq * 8 + e;
      float v = (ci < 16) ? ut[(size_t)(rowBase + r) * 16 + ci] * dtv
                          : (ci == 16 ? 1.f : 0.f);
      o[e] = (bf16)v;
    }
    *(bf16x8*)&Ht[t * 8] = o;
  }
  lds_barrier();

  f32x4 accZ[4][5];
  #pragma unroll
  for (int i = 0; i < 4; ++i)
    #pragma unroll
    for (int j = 0; j < 5; ++j)
      #pragma unroll
      for (int r = 0; r < 4; ++r) accZ[i][j][r] = 0.f;

  #pragma unroll 1
  for (int c = 0; c < 4; ++c) {
    // ---- phase 1: acc1 = X * W1eff_c^T (barrier-free; B-frags reused 4x) ----
    f32x4 acc1[4][2];
    #pragma unroll
    for (int i = 0; i < 4; ++i)
      #pragma unroll
      for (int j = 0; j < 2; ++j)
        #pragma unroll
        for (int r = 0; r < 4; ++r) acc1[i][j][r] = 0.f;

    #pragma unroll
    for (int kk = 0; kk < 10; ++kk) {
      bf16x8 bfr[2];
      #pragma unroll
      for (int j = 0; j < 2; ++j) {
        int G = c * 8 + w * 2 + j;
        bfr[j] = *(const bf16x8*)&W1sw[(size_t)(((G * 10 + kk) * 4 + q) * 16 + m16) * 8];
      }
      bf16x8 af[4];
      #pragma unroll
      for (int i = 0; i < 4; ++i) {
        int row = i * 16 + m16;
        af[i] = *(const bf16x8*)&Xs[(size_t)((kk * 64 + row) * 4 + (q ^ ((row >> 1) & 3))) * 8];
      }
      #pragma unroll
      for (int i = 0; i < 4; ++i)
        #pragma unroll
        for (int j = 0; j < 2; ++j)
          acc1[i][j] = __builtin_amdgcn_mfma_f32_16x16x32_bf16(af[i], bfr[j], acc1[i][j], 0, 0, 0);
    }

    // ---- +b1, per-lane LN partials (2 cols), shfl-reduce across m16 groups,
    //      write w-indexed slot (no cross-wave race)
    {
      float b0v = sb1[c * 128 + w * 32 + m16];
      float b1v = sb1[c * 128 + w * 32 + 16 + m16];
      const int slot = w * 4 + (m16 >> 2);
      #pragma unroll
      for (int i = 0; i < 4; ++i) {
        #pragma unroll
        for (int rr = 0; rr < 4; ++rr) {
          float v0 = acc1[i][0][rr] + b0v;
          float v1 = acc1[i][1][rr] + b1v;
          acc1[i][0][rr] = v0;
          acc1[i][1][rr] = v1;
          float s  = v0 + v1;
          float s2 = fmaf(v0, v0, v1 * v1);
          s  += __shfl_xor(s, 1);  s  += __shfl_xor(s, 2);
          s2 += __shfl_xor(s2, 1); s2 += __shfl_xor(s2, 2);
          if ((m16 & 3) == 0) {
            int row = i * 16 + q * 4 + rr;
            spart[row * 17 + slot] = make_float2(s, s2);
          }
        }
      }
    }
    lds_barrier();   // B1: spart ready; also separates prev phase-2 Hc reads
    if (t < 64) {
      float s = 0.f, s2 = 0.f;
      #pragma unroll
      for (int m = 0; m < 16; ++m) {
        float2 p = spart[t * 17 + m];
        s += p.x; s2 += p.y;
      }
      float mu = s * 0.0078125f;
      float var = s2 * 0.0078125f - mu * mu;
      smu[t] = mu;
      srs[t] = rsqrtf(fmaxf(var, 0.f) + LN_EPS);
    }
    lds_barrier();   // B2: mu/rs ready

    // ---- LN + GELU in-register, write H to Hc (swizzled, u16 scatter)
    {
      float g0 = sgam[c * 128 + w * 32 + m16];
      float g1 = sgam[c * 128 + w * 32 + 16 + m16];
      float be0 = sbet[c * 128 + w * 32 + m16];
      float be1 = sbet[c * 128 + w * 32 + 16 + m16];
      int col0 = w * 32 + m16, col1 = w * 32 + 16 + m16;
      int cq0 = col0 >> 3, cq1 = col1 >> 3;
      #pragma unroll
      for (int i = 0; i < 4; ++i) {
        f32x4 mu4 = *(const f32x4*)&smu[i * 16 + q * 4];
        f32x4 rs4 = *(const f32x4*)&srs[i * 16 + q * 4];
        #pragma unroll
        for (int rr = 0; rr < 4; ++rr) {
          int row = i * 16 + q * 4 + rr;
          int sw = (row >> 1) & 3;
          float v0 = fmaf((acc1[i][0][rr] - mu4[rr]) * rs4[rr], g0, be0);
          float v1 = fmaf((acc1[i][1][rr] - mu4[rr]) * rs4[rr], g1, be1);
          Hc[row * 128 + (cq0 ^ sw) * 8 + (col0 & 7)] = (bf16)gelu_exact(v0);
          Hc[row * 128 + (cq1 ^ sw) * 8 + (col1 & 7)] = (bf16)gelu_exact(v1);
        }
      }
    }
    lds_barrier();   // B3: Hc ready

    // ---- phase 2: accZ += H_c * P_c^T (barrier-free; B-frags reused 4x) ----
    #pragma unroll
    for (int t2 = 0; t2 < 4; ++t2) {
      int kk2 = c * 4 + t2;
      bf16x8 af[4], bfr[5];
      #pragma unroll
      for (int i = 0; i < 4; ++i) {
        int row = i * 16 + m16;
        af[i] = *(const bf16x8*)&Hc[row * 128 + (((t2 * 4 + q) ^ ((row >> 1) & 3))) * 8];
      }
      #pragma unroll
      for (int j = 0; j < 5; ++j) {
        int G2 = w * 5 + j;
        bfr[j] = *(const bf16x8*)&Psw[(size_t)(((G2 * 17 + kk2) * 4 + q) * 16 + m16) * 8];
      }
      #pragma unroll
      for (int i = 0; i < 4; ++i)
        #pragma unroll
        for (int j = 0; j < 5; ++j)
          accZ[i][j] = __builtin_amdgcn_mfma_f32_16x16x32_bf16(af[i], bfr[j], accZ[i][j], 0, 0, 0);
    }
  }

  // ---- K tail (kk2 = 16): A = [ut*dt | 1 | 0] from Ht ----
  {
    bf16x8 af[4], bfr[5];
    #pragma unroll
    for (int i = 0; i < 4; ++i) {
      int row = i * 16 + m16;
      af[i] = *(const bf16x8*)&Ht[(row * 4 + (q ^ ((row >> 1) & 3))) * 8];
    }
    #pragma unroll
    for (int j = 0; j < 5; ++j) {
      int G2 = w * 5 + j;
      bfr[j] = *(const bf16x8*)&Psw[(size_t)(((G2 * 17 + 16) * 4 + q) * 16 + m16) * 8];
    }
    #pragma unroll
    for (int i = 0; i < 4; ++i)
      #pragma unroll
      for (int j = 0; j < 5; ++j)
        accZ[i][j] = __builtin_amdgcn_mfma_f32_16x16x32_bf16(af[i], bfr[j], accZ[i][j], 0, 0, 0);
  }

  // ---- store Z / yt ----
  #pragma unroll
  for (int i = 0; i < 4; ++i)
    #pragma unroll
    for (int j = 0; j < 5; ++j) {
      int col = (w * 5 + j) * 16 + m16;
      #pragma unroll
      for (int rr = 0; rr < 4; ++rr) {
        int row = rowBase + i * 16 + q * 4 + rr;
        if (col < 256)      Z[(size_t)row * 256 + col] = accZ[i][j][rr];
        else if (col < 281) yt[(size_t)row * 25 + (col - 256)] = accZ[i][j][rr];
      }
    }
}

extern "C" void kernel_launch(void* const* d_in, const int* in_sizes, int n_in,
                              void* d_out, int out_size, void* d_ws, size_t ws_size,
                              hipStream_t stream) {
  const float* zdyn  = (const float*)d_in[0];
  const float* zst   = (const float*)d_in[1];
  const float* dtp   = (const float*)d_in[2];
  const float* ut    = (const float*)d_in[3];
  const float* gates = (const float*)d_in[4];
  const float* W1    = (const float*)d_in[5];
  const float* b1    = (const float*)d_in[6];
  const float* gamma = (const float*)d_in[7];
  const float* beta  = (const float*)d_in[8];
  const float* W2    = (const float*)d_in[9];
  const float* b2    = (const float*)d_in[10];
  // d_in[11], d_in[12] (lam_real/lam_imag) dead: h0 = 0
  const float* Bmat  = (const float*)d_in[13];
  const float* Wout  = (const float*)d_in[14];
  const float* Cm    = (const float*)d_in[15];
  const float* Dm    = (const float*)d_in[16];

  char* ws = (char*)d_ws;
  bf16*  W1sw = (bf16*)(ws);
  bf16*  Psw  = (bf16*)(ws + 327680);
  float* Mtmp = (float*)(ws + 675840);
  float* cvec = (float*)(ws + 806912);
  float* CW   = (float*)(ws + 807936);

  float* Z  = (float*)d_out;
  float* yt = Z + (size_t)B_ROWS * 256;

  hipLaunchKernelGGL(prep_weights1, dim3(128), dim3(256), 0, stream,
                     gates, W1, Bmat, W2, b2, Wout, Cm, W1sw, Mtmp, cvec, CW);
  hipLaunchKernelGGL(prep_weights2, dim3(256), dim3(256), 0, stream,
                     Wout, Bmat, Mtmp, cvec, CW, Dm, Psw);
  hipLaunchKernelGGL(fused_main, dim3(512), dim3(256), 0, stream,
                     zdyn, zst, ut, dtp, W1sw, Psw, b1, gamma, beta, Z, yt);
}